// Round 8
// baseline (322.713 us; speedup 1.0000x reference)
//
#include <hip/hip_runtime.h>

typedef float          f32x4    __attribute__((ext_vector_type(4)));
typedef float          float8v  __attribute__((ext_vector_type(8)));
typedef unsigned short ushort8v __attribute__((ext_vector_type(8)));
typedef __bf16         bf16x8   __attribute__((ext_vector_type(8)));

__device__ __forceinline__ unsigned short f2b(float x) {
  union { __bf16 b; unsigned short u; } v;
  v.b = (__bf16)x;                       // hw v_cvt (RNE) on gfx950
  return v.u;
}
__device__ __forceinline__ float b2f(unsigned short h) {
  union { unsigned u; float f; } v; v.u = ((unsigned)h) << 16;
  return v.f;
}

// async global->LDS, 16B per lane; LDS dest = wave-uniform base + lane*16
__device__ __forceinline__ void g2lds16(const unsigned short* g,
                                        unsigned short* l) {
  __builtin_amdgcn_global_load_lds(
      (const __attribute__((address_space(1))) unsigned int*)g,
      (__attribute__((address_space(3))) unsigned int*)l, 16, 0, 0);
}

// ---------- prep kernel: f32->bf16 cvt + all 6 weight transposes ----------
// One launch replaces 7. Blocks [0, cvtb): cvt 8 elems/thread.
// Blocks [cvtb, cvtb+864): W(f32)[K][N] -> WT(bf16)[N][K] 64x64 tiles:
//   wqr(256) | wkr(256) | wkvc(32, N=128) | wkc(32, K=128) | wvc(32) | wo(256)
__global__ __launch_bounds__(256) void prep_kernel(
    const float* __restrict__ X, unsigned short* __restrict__ Xb, int cvtb,
    int n8,
    const float* __restrict__ w0, unsigned short* __restrict__ t0,
    const float* __restrict__ w1, unsigned short* __restrict__ t1,
    const float* __restrict__ w2, unsigned short* __restrict__ t2,
    const float* __restrict__ w3, unsigned short* __restrict__ t3,
    const float* __restrict__ w4, unsigned short* __restrict__ t4,
    const float* __restrict__ w5, unsigned short* __restrict__ t5) {
  __shared__ unsigned short T[64 * 72];
  const int tid = threadIdx.x;
  int blk = blockIdx.x;
  if (blk < cvtb) {
    int i = blk * 256 + tid;
    if (i >= n8) return;
    float8v v = reinterpret_cast<const float8v*>(X)[i];
    ushort8v h;
#pragma unroll
    for (int j = 0; j < 8; ++j) h[j] = f2b(v[j]);
    reinterpret_cast<ushort8v*>(Xb)[i] = h;
    return;
  }
  blk -= cvtb;
  const float* W; unsigned short* WT; int K, N, bx, by;
  if (blk < 256)      { W = w0; WT = t0; K = 1024; N = 1024; bx = blk & 15;         by = blk >> 4; }
  else if (blk < 512) { W = w1; WT = t1; K = 1024; N = 1024; bx = (blk - 256) & 15; by = (blk - 256) >> 4; }
  else if (blk < 544) { W = w2; WT = t2; K = 1024; N = 128;  bx = (blk - 512) & 1;  by = (blk - 512) >> 1; }
  else if (blk < 576) { W = w3; WT = t3; K = 128;  N = 1024; bx = (blk - 544) & 15; by = (blk - 544) >> 4; }
  else if (blk < 608) { W = w4; WT = t4; K = 128;  N = 1024; bx = (blk - 576) & 15; by = (blk - 576) >> 4; }
  else                { W = w5; WT = t5; K = 1024; N = 1024; bx = (blk - 608) & 15; by = (blk - 608) >> 4; }
  const int n0 = bx * 64, k0 = by * 64;
#pragma unroll
  for (int it = 0; it < 2; ++it) {
    int c = tid + it * 256;               // [0,512)
    int r = c >> 3, cc = c & 7;
    float8v v = *reinterpret_cast<const float8v*>(
        &W[(size_t)(k0 + r) * N + n0 + cc * 8]);
    ushort8v h;
#pragma unroll
    for (int j = 0; j < 8; ++j) h[j] = f2b(v[j]);
    *reinterpret_cast<ushort8v*>(&T[r * 72 + cc * 8]) = h;
  }
  __syncthreads();
#pragma unroll
  for (int it = 0; it < 2; ++it) {
    int c = tid + it * 256;
    int n = c >> 3, kc = c & 7;
    ushort8v y;
#pragma unroll
    for (int j = 0; j < 8; ++j) y[j] = T[(kc * 8 + j) * 72 + n];
    *reinterpret_cast<ushort8v*>(&WT[(size_t)(n0 + n) * K + k0 + kc * 8]) = y;
  }
}

// ---------------- generic gemm_bt (single-buffer) ----------------
template <int TM, typename CT, bool ACC>
__global__ __launch_bounds__(256) void gemm_bt(
    const unsigned short* __restrict__ A, const unsigned short* __restrict__ Bt,
    CT* __restrict__ C, int M, int N, int K) {
  __shared__ unsigned short As[TM * 64];
  __shared__ unsigned short Bs[128 * 64];
  const int tid = threadIdx.x;
  const int m0 = blockIdx.y * TM, n0 = blockIdx.x * 128;
  const int wave = tid >> 6, lane = tid & 63;
  const int wm = (wave >> 1) * (TM / 2), wn = (wave & 1) * 64;
  const int l16 = lane & 15, quad = lane >> 4;
  constexpr int MI = TM / 32;

  f32x4 acc[MI][4];
#pragma unroll
  for (int i = 0; i < MI; ++i)
#pragma unroll
    for (int j = 0; j < 4; ++j)
#pragma unroll
      for (int r = 0; r < 4; ++r) acc[i][j][r] = 0.f;

  for (int k0 = 0; k0 < K; k0 += 64) {
    __syncthreads();
#pragma unroll
    for (int it = 0; it < TM * 8 / 256; ++it) {
      int c = it * 256 + tid;
      int m = c >> 3, kc = (c & 7) ^ (m & 7);
      g2lds16(&A[(size_t)(m0 + m) * K + k0 + kc * 8], &As[c * 8]);
    }
#pragma unroll
    for (int it = 0; it < 4; ++it) {
      int c = it * 256 + tid;
      int n = c >> 3, kc = (c & 7) ^ (n & 7);
      g2lds16(&Bt[(size_t)(n0 + n) * K + k0 + kc * 8], &Bs[c * 8]);
    }
    __syncthreads();

#pragma unroll
    for (int ks = 0; ks < 2; ++ks) {
      bf16x8 af[MI], bfr[4];
#pragma unroll
      for (int mi = 0; mi < MI; ++mi) {
        int m = wm + mi * 16 + l16;
        af[mi] = *reinterpret_cast<const bf16x8*>(
            &As[(m * 8 + ((ks * 4 + quad) ^ (m & 7))) * 8]);
      }
#pragma unroll
      for (int ni = 0; ni < 4; ++ni) {
        int n = wn + ni * 16 + l16;
        bfr[ni] = *reinterpret_cast<const bf16x8*>(
            &Bs[(n * 8 + ((ks * 4 + quad) ^ (n & 7))) * 8]);
      }
#pragma unroll
      for (int mi = 0; mi < MI; ++mi)
#pragma unroll
        for (int ni = 0; ni < 4; ++ni)
          acc[mi][ni] = __builtin_amdgcn_mfma_f32_16x16x32_bf16(
              af[mi], bfr[ni], acc[mi][ni], 0, 0, 0);
    }
  }

#pragma unroll
  for (int mi = 0; mi < MI; ++mi)
#pragma unroll
    for (int ni = 0; ni < 4; ++ni) {
      int row = m0 + wm + mi * 16 + quad * 4;
      int col = n0 + wn + ni * 16 + l16;
#pragma unroll
      for (int r = 0; r < 4; ++r) {
        size_t idx = (size_t)(row + r) * N + col;
        float val = acc[mi][ni][r];
        if constexpr (sizeof(CT) == 2) {
          if constexpr (ACC) val += b2f(C[idx]);
          C[idx] = f2b(val);
        } else {
          if constexpr (ACC) val += C[idx];
          C[idx] = val;
        }
      }
    }
}

// -- fused GEMM #1 + rope: [q_r|k_r|c_kv] = X @ [wqr|wkr|wkvc]^T, rope in --
// epilogue. For q/k outputs, rotate-half partner col^32 = acc[mi][ni^2][r]
// (same lane), so rope is fully in-register on f32 acc values:
//   out[col]    = (v1*cq - v2*ck) * s
//   out[col+32] = (v2*cq + v1*ck) * s     (s = 0.125*log2e for q, 1 for k)
// cq = cos(tq[row]*f), ck = cos(tk[row]*f), f = 10000^(-(col&31)/32).
__global__ __launch_bounds__(256) void gemm_fused3(
    const unsigned short* __restrict__ A, const unsigned short* __restrict__ Bt,
    unsigned short* __restrict__ Cq, unsigned short* __restrict__ Ck,
    unsigned short* __restrict__ Cc, const float* __restrict__ tq,
    const float* __restrict__ tk, int K) {
  __shared__ unsigned short As[1024 * 8];
  __shared__ unsigned short Bs[1024 * 8];
  const int tid = threadIdx.x;
  const int m0 = blockIdx.y * 128, n0 = blockIdx.x * 128;
  const int wave = tid >> 6, lane = tid & 63;
  const int wm = (wave >> 1) * 64, wn = (wave & 1) * 64;
  const int l16 = lane & 15, quad = lane >> 4;

  f32x4 acc[4][4];
#pragma unroll
  for (int i = 0; i < 4; ++i)
#pragma unroll
    for (int j = 0; j < 4; ++j)
#pragma unroll
      for (int r = 0; r < 4; ++r) acc[i][j][r] = 0.f;

  for (int k0 = 0; k0 < K; k0 += 64) {
    __syncthreads();
#pragma unroll
    for (int it = 0; it < 4; ++it) {
      int c = it * 256 + tid;
      int m = c >> 3, kc = (c & 7) ^ (m & 7);
      g2lds16(&A[(size_t)(m0 + m) * K + k0 + kc * 8], &As[c * 8]);
    }
#pragma unroll
    for (int it = 0; it < 4; ++it) {
      int c = it * 256 + tid;
      int n = c >> 3, kc = (c & 7) ^ (n & 7);
      g2lds16(&Bt[(size_t)(n0 + n) * K + k0 + kc * 8], &Bs[c * 8]);
    }
    __syncthreads();

#pragma unroll
    for (int ks = 0; ks < 2; ++ks) {
      bf16x8 af[4], bfr[4];
#pragma unroll
      for (int mi = 0; mi < 4; ++mi) {
        int m = wm + mi * 16 + l16;
        af[mi] = *reinterpret_cast<const bf16x8*>(
            &As[(m * 8 + ((ks * 4 + quad) ^ (m & 7))) * 8]);
      }
#pragma unroll
      for (int ni = 0; ni < 4; ++ni) {
        int n = wn + ni * 16 + l16;
        bfr[ni] = *reinterpret_cast<const bf16x8*>(
            &Bs[(n * 8 + ((ks * 4 + quad) ^ (n & 7))) * 8]);
      }
#pragma unroll
      for (int mi = 0; mi < 4; ++mi)
#pragma unroll
        for (int ni = 0; ni < 4; ++ni)
          acc[mi][ni] = __builtin_amdgcn_mfma_f32_16x16x32_bf16(
              af[mi], bfr[ni], acc[mi][ni], 0, 0, 0);
    }
  }

  if (n0 < 2048) {
    // rope path (q or k)
    const bool isq = (n0 < 1024);
    unsigned short* dst = isq ? Cq : Ck;
    const int cb = isq ? 0 : 1024;
    const float s = isq ? 0.18033688011112042f : 1.0f;  // 0.125*log2(e) | 1
    const float f0 = exp2f(-(float)l16 * (13.287712379549449f / 32.f));
    const float f1 = exp2f(-(float)(l16 + 16) * (13.287712379549449f / 32.f));
#pragma unroll
    for (int mi = 0; mi < 4; ++mi)
#pragma unroll
      for (int r = 0; r < 4; ++r) {
        int row = m0 + wm + mi * 16 + quad * 4 + r;
        float tqm = tq[row], tkm = tk[row];
#pragma unroll
        for (int np = 0; np < 2; ++np) {
          float f = np ? f1 : f0;
          float cq = cosf(tqm * f), ck = cosf(tkm * f);
          float v1 = acc[mi][np][r], v2 = acc[mi][np + 2][r];
          int col = n0 - cb + wn + np * 16 + l16;
          dst[(size_t)row * 1024 + col]      = f2b((v1 * cq - v2 * ck) * s);
          dst[(size_t)row * 1024 + col + 32] = f2b((v2 * cq + v1 * ck) * s);
        }
      }
  } else {
    // c_kv plain store
#pragma unroll
    for (int mi = 0; mi < 4; ++mi)
#pragma unroll
      for (int ni = 0; ni < 4; ++ni) {
        int row = m0 + wm + mi * 16 + quad * 4;
        int col = n0 - 2048 + wn + ni * 16 + l16;
#pragma unroll
        for (int r = 0; r < 4; ++r)
          Cc[(size_t)(row + r) * 128 + col] = f2b(acc[mi][ni][r]);
      }
  }
}

// ------- fused GEMM #2: [k_c(acc->ksb) | v_c] = ckv @ [wkc|wvc]^T -------
__global__ __launch_bounds__(256) void gemm_fused2(
    const unsigned short* __restrict__ A, const unsigned short* __restrict__ Bt,
    unsigned short* __restrict__ Ck, unsigned short* __restrict__ Cv, int K) {
  __shared__ unsigned short As[1024 * 8];
  __shared__ unsigned short Bs[1024 * 8];
  const int tid = threadIdx.x;
  const int m0 = blockIdx.y * 128, n0 = blockIdx.x * 128;
  const int wave = tid >> 6, lane = tid & 63;
  const int wm = (wave >> 1) * 64, wn = (wave & 1) * 64;
  const int l16 = lane & 15, quad = lane >> 4;

  f32x4 acc[4][4];
#pragma unroll
  for (int i = 0; i < 4; ++i)
#pragma unroll
    for (int j = 0; j < 4; ++j)
#pragma unroll
      for (int r = 0; r < 4; ++r) acc[i][j][r] = 0.f;

  for (int k0 = 0; k0 < K; k0 += 64) {
    __syncthreads();
#pragma unroll
    for (int it = 0; it < 4; ++it) {
      int c = it * 256 + tid;
      int m = c >> 3, kc = (c & 7) ^ (m & 7);
      g2lds16(&A[(size_t)(m0 + m) * K + k0 + kc * 8], &As[c * 8]);
    }
#pragma unroll
    for (int it = 0; it < 4; ++it) {
      int c = it * 256 + tid;
      int n = c >> 3, kc = (c & 7) ^ (n & 7);
      g2lds16(&Bt[(size_t)(n0 + n) * K + k0 + kc * 8], &Bs[c * 8]);
    }
    __syncthreads();

#pragma unroll
    for (int ks = 0; ks < 2; ++ks) {
      bf16x8 af[4], bfr[4];
#pragma unroll
      for (int mi = 0; mi < 4; ++mi) {
        int m = wm + mi * 16 + l16;
        af[mi] = *reinterpret_cast<const bf16x8*>(
            &As[(m * 8 + ((ks * 4 + quad) ^ (m & 7))) * 8]);
      }
#pragma unroll
      for (int ni = 0; ni < 4; ++ni) {
        int n = wn + ni * 16 + l16;
        bfr[ni] = *reinterpret_cast<const bf16x8*>(
            &Bs[(n * 8 + ((ks * 4 + quad) ^ (n & 7))) * 8]);
      }
#pragma unroll
      for (int mi = 0; mi < 4; ++mi)
#pragma unroll
        for (int ni = 0; ni < 4; ++ni)
          acc[mi][ni] = __builtin_amdgcn_mfma_f32_16x16x32_bf16(
              af[mi], bfr[ni], acc[mi][ni], 0, 0, 0);
    }
  }

  const bool first = (n0 < 1024);
  unsigned short* dst = first ? Ck : Cv;
  int cb = first ? 0 : 1024;
#pragma unroll
  for (int mi = 0; mi < 4; ++mi)
#pragma unroll
    for (int ni = 0; ni < 4; ++ni) {
      int row = m0 + wm + mi * 16 + quad * 4;
      int col = n0 - cb + wn + ni * 16 + l16;
#pragma unroll
      for (int r = 0; r < 4; ++r) {
        size_t idx = (size_t)(row + r) * 1024 + col;
        float val = acc[mi][ni][r];
        if (first) val += b2f(dst[idx]);   // accumulate onto rope'd k_r
        dst[idx] = f2b(val);
      }
    }
}

// ------ V transpose + key-permute: [b,l,h,d] -> Vt[b,h,d,sigma^-1(l)] ------
// sigma^-1: s = [k5 k3 k2 k4 k1 k0] (bits 5..0). Output position group g
// (8 consecutive s = g*8+e) gathers keys
//   key(g,e) = (g>>2)<<5 | (e>>2)<<4 | ((g>>1)&1)<<3 | (g&1)<<2 | (e&3)
// so each 16B store stays fully vectorized (b128).
__global__ __launch_bounds__(256) void vtrans_kernel(
    const unsigned short* __restrict__ v, unsigned short* __restrict__ vt,
    int L) {
  __shared__ unsigned short T[64 * 72];
  const int tid = threadIdx.x;
  const int l0 = blockIdx.x * 64, bh = blockIdx.y;
  const size_t inbase = ((size_t)(bh >> 4) * L) * 1024 + (bh & 15) * 64;
  const size_t outbase = (size_t)bh * 64 * L;
#pragma unroll
  for (int it = 0; it < 2; ++it) {
    int c = tid + it * 256;               // [0,512)
    int l = c >> 3, dc = c & 7;
    ushort8v x = *reinterpret_cast<const ushort8v*>(
        &v[inbase + (size_t)(l0 + l) * 1024 + dc * 8]);
    *reinterpret_cast<ushort8v*>(&T[l * 72 + dc * 8]) = x;
  }
  __syncthreads();
#pragma unroll
  for (int it = 0; it < 2; ++it) {
    int c = tid + it * 256;
    int d = c >> 3, g = c & 7;
    ushort8v y;
#pragma unroll
    for (int e = 0; e < 8; ++e) {
      int k = ((g >> 2) << 5) | ((e >> 2) << 4) | (((g >> 1) & 1) << 3) |
              ((g & 1) << 2) | (e & 3);
      y[e] = T[k * 72 + d];
    }
    *reinterpret_cast<ushort8v*>(&vt[outbase + (size_t)d * L + l0 + g * 8]) = y;
  }
}

// ---------- flash v15: 8 waves, 512 thr, in-block KV-split ----------
// waves 0-3 process KV [0,L/2), waves 4-7 KV [L/2,L), same 128 q rows.
// No max-subtraction -> O and l additive over key ranges: half-1 waves
// write (oacc,lacc) to LDS once at the end; half-0 adds, normalizes, stores.
__global__ __launch_bounds__(512) void flash15_kernel(
    const unsigned short* __restrict__ qs, const unsigned short* __restrict__ ks,
    const unsigned short* __restrict__ vt, unsigned short* __restrict__ o,
    int L) {
  // [kv={K,V}][half][dbuf][64x64 swizzled]  = 64KB total
  __shared__ unsigned short KV[2][2][2][512 * 8];
  const int tid = threadIdx.x;
  const int wave = tid >> 6, lane = tid & 63;
  const int half = wave >> 2;                  // KV half this wave works on
  const int l16 = lane & 15, quad = lane >> 4;
  const int bh = blockIdx.y;                   // b*16 + h
  const int qb = blockIdx.x * 128 + (wave & 3) * 32;  // this wave's 32 q rows
  const size_t base = ((size_t)(bh >> 4) * L) * 1024 + (bh & 15) * 64;
  const size_t vtbase = (size_t)bh * 64 * L;
  const int kvoff = half * (L >> 1);           // key offset of this half
  const int sid = tid & 255;                   // staging lane within half

  bf16x8 aq[2][2];
#pragma unroll
  for (int mt = 0; mt < 2; ++mt) {
    size_t qrow = base + (size_t)(qb + mt * 16 + l16) * 1024;
    aq[mt][0] = *reinterpret_cast<const bf16x8*>(&qs[qrow + quad * 8]);
    aq[mt][1] = *reinterpret_cast<const bf16x8*>(&qs[qrow + 32 + quad * 8]);
  }

  ushort8v onesu;
#pragma unroll
  for (int j = 0; j < 8; ++j) onesu[j] = 0x3F80;  // bf16 1.0
  bf16x8 ones = *reinterpret_cast<bf16x8*>(&onesu);

  f32x4 oacc[2][4];
  f32x4 lacc[2];
#pragma unroll
  for (int mt = 0; mt < 2; ++mt) {
#pragma unroll
    for (int r = 0; r < 4; ++r) lacc[mt][r] = 0.f;
#pragma unroll
    for (int nt = 0; nt < 4; ++nt)
#pragma unroll
      for (int r = 0; r < 4; ++r) oacc[mt][nt][r] = 0.f;
  }

  const int T = L / 128;   // 16 tiles per half
  // prologue: each half's 256 threads stage that half's tile 0
#pragma unroll
  for (int it = 0; it < 2; ++it) {
    int c = it * 256 + sid;                    // [0,512)
    int key = c >> 3, dc = (c & 7) ^ (key & 7);
    g2lds16(&ks[base + (size_t)(kvoff + key) * 1024 + dc * 8],
            &KV[0][half][0][c * 8]);
  }
#pragma unroll
  for (int it = 0; it < 2; ++it) {
    int c = it * 256 + sid;
    int d = c >> 3, kc = (c & 7) ^ (d & 7);
    g2lds16(&vt[vtbase + (size_t)d * L + kvoff + kc * 8],
            &KV[1][half][0][c * 8]);
  }

  for (int t = 0; t < T; ++t) {
    __syncthreads();   // drains stage(t); prior-buf readers done
    if (t + 1 < T) {
      int k0 = kvoff + (t + 1) * 64, nb = (t + 1) & 1;
#pragma unroll
      for (int it = 0; it < 2; ++it) {
        int c = it * 256 + sid;
        int key = c >> 3, dc = (c & 7) ^ (key & 7);
        g2lds16(&ks[base + (size_t)(k0 + key) * 1024 + dc * 8],
                &KV[0][half][nb][c * 8]);
      }
#pragma unroll
      for (int it = 0; it < 2; ++it) {
        int c = it * 256 + sid;
        int d = c >> 3, kc = (c & 7) ^ (d & 7);
        g2lds16(&vt[vtbase + (size_t)d * L + k0 + kc * 8],
                &KV[1][half][nb][c * 8]);
      }
    }
    const int cb = t & 1;
    const unsigned short* Ks = &KV[0][half][cb][0];
    const unsigned short* Vs = &KV[1][half][cb][0];

    // S^T = K Q^T for BOTH m-tiles; K fragments read once.
    f32x4 st[2][4];
#pragma unroll
    for (int nt = 0; nt < 4; ++nt) {
      int key = nt * 16 + l16;
      int dc0 = quad ^ (key & 7);
      int dc1 = (4 + quad) ^ (key & 7);
      bf16x8 bk0 = *reinterpret_cast<const bf16x8*>(&Ks[(key * 8 + dc0) * 8]);
      bf16x8 bk1 = *reinterpret_cast<const bf16x8*>(&Ks[(key * 8 + dc1) * 8]);
#pragma unroll
      for (int mt = 0; mt < 2; ++mt) {
        f32x4 z; z[0] = z[1] = z[2] = z[3] = 0.f;
        z = __builtin_amdgcn_mfma_f32_16x16x32_bf16(bk0, aq[mt][0], z, 0, 0, 0);
        z = __builtin_amdgcn_mfma_f32_16x16x32_bf16(bk1, aq[mt][1], z, 0, 0, 0);
        st[mt][nt] = z;
      }
    }

    // exp2 -> ap frags by pure register renaming (key-permutation sigma)
    bf16x8 ap[2][2];
#pragma unroll
    for (int mt = 0; mt < 2; ++mt) {
#pragma unroll
      for (int hf = 0; hf < 2; ++hf)
#pragma unroll
        for (int w = 0; w < 4; ++w) {
          int nt = 2 * hf + (w >> 1), p = w & 1;
          ap[mt][hf][2 * w] =
              (__bf16)__builtin_amdgcn_exp2f(st[mt][nt][2 * p]);
          ap[mt][hf][2 * w + 1] =
              (__bf16)__builtin_amdgcn_exp2f(st[mt][nt][2 * p + 1]);
        }
      lacc[mt] = __builtin_amdgcn_mfma_f32_16x16x32_bf16(ap[mt][0], ones,
                                                         lacc[mt], 0, 0, 0);
      lacc[mt] = __builtin_amdgcn_mfma_f32_16x16x32_bf16(ap[mt][1], ones,
                                                         lacc[mt], 0, 0, 0);
    }

    // O += P V (V fragments read once, reused by both m-tiles)
#pragma unroll
    for (int nt = 0; nt < 4; ++nt) {
      int d = nt * 16 + l16;
#pragma unroll
      for (int hf = 0; hf < 2; ++hf) {
        int kc = (hf * 4 + quad) ^ (d & 7);
        bf16x8 bv = *reinterpret_cast<const bf16x8*>(&Vs[(d * 8 + kc) * 8]);
#pragma unroll
        for (int mt = 0; mt < 2; ++mt)
          oacc[mt][nt] = __builtin_amdgcn_mfma_f32_16x16x32_bf16(
              ap[mt][hf], bv, oacc[mt][nt], 0, 0, 0);
      }
    }
  }

  // ---- combine halves in LDS (O and l are additive; no max used) ----
  __syncthreads();                 // all K/V reads done; LDS reusable
  float* cbuf = (float*)&KV[0][0][0][0];   // 45056B needed <= 64KB
  if (half == 1) {
    int slot = ((wave - 4) * 64 + lane) * 44;   // stride 44 f32 (16B-aligned)
#pragma unroll
    for (int mt = 0; mt < 2; ++mt) {
#pragma unroll
      for (int nt = 0; nt < 4; ++nt)
        *reinterpret_cast<f32x4*>(&cbuf[slot + (mt * 4 + nt) * 4]) =
            oacc[mt][nt];
      *reinterpret_cast<f32x4*>(&cbuf[slot + 32 + mt * 4]) = lacc[mt];
    }
  }
  __syncthreads();
  if (half == 0) {
    int slot = (wave * 64 + lane) * 44;
#pragma unroll
    for (int mt = 0; mt < 2; ++mt) {
#pragma unroll
      for (int nt = 0; nt < 4; ++nt) {
        f32x4 ov = *reinterpret_cast<const f32x4*>(
            &cbuf[slot + (mt * 4 + nt) * 4]);
#pragma unroll
        for (int r = 0; r < 4; ++r) oacc[mt][nt][r] += ov[r];
      }
      f32x4 lv = *reinterpret_cast<const f32x4*>(&cbuf[slot + 32 + mt * 4]);
#pragma unroll
      for (int r = 0; r < 4; ++r) lacc[mt][r] += lv[r];
    }
#pragma unroll
    for (int mt = 0; mt < 2; ++mt)
#pragma unroll
      for (int r = 0; r < 4; ++r) {
        float inv = __builtin_amdgcn_rcpf(lacc[mt][r]);
        int q = qb + mt * 16 + quad * 4 + r;
#pragma unroll
        for (int nt = 0; nt < 4; ++nt)
          o[base + (size_t)q * 1024 + nt * 16 + l16] =
              f2b(oacc[mt][nt][r] * inv);
      }
  }
}

// ---------------- driver ----------------
extern "C" void kernel_launch(void* const* d_in, const int* in_sizes, int n_in,
                              void* d_out, int out_size, void* d_ws, size_t ws_size,
                              hipStream_t stream) {
  const float* X    = (const float*)d_in[0];
  const float* tq   = (const float*)d_in[1];
  const float* tk   = (const float*)d_in[2];
  const float* wkvc = (const float*)d_in[3];
  const float* wkc  = (const float*)d_in[4];
  const float* wvc  = (const float*)d_in[5];
  const float* wqr  = (const float*)d_in[6];
  const float* wkr  = (const float*)d_in[7];
  const float* wo   = (const float*)d_in[8];

  const int D = 1024, DC = 128, L = 2048;
  const int M = in_sizes[0] / D;       // B*L
  const int B = M / L;
  const int NBH = B * 16;
  (void)n_in; (void)out_size; (void)ws_size;

  unsigned short* p = (unsigned short*)d_ws;
  auto take = [&](size_t n) { unsigned short* r = p; p += n; return r; };
  unsigned short* Xb    = take((size_t)M * D);
  unsigned short* qsb   = take((size_t)M * D);
  unsigned short* ksb   = take((size_t)M * D);
  unsigned short* vcb   = take((size_t)M * D);
  unsigned short* ckv   = take((size_t)M * DC);
  unsigned short* Wbig  = take((size_t)(2 * D + DC) * D);   // [wqr|wkr|wkvc]^T
  unsigned short* Wkcvc = take((size_t)(2 * D) * DC);       // [wkc|wvc]^T
  unsigned short* WoT   = take((size_t)D * D);
  unsigned short* vtb   = Xb;   // Xb dead after fused3 gemm
  unsigned short* obuf  = vcb;  // vcb dead after vtrans; flash O lands here

  // prep: cvt + all 6 weight transposes in ONE launch
  const int n8 = M * D / 8;
  const int cvtb = (n8 + 255) / 256;
  prep_kernel<<<cvtb + 864, 256, 0, stream>>>(
      X, Xb, cvtb, n8,
      wqr,  Wbig,
      wkr,  Wbig + (size_t)D * D,
      wkvc, Wbig + (size_t)2 * D * D,
      wkc,  Wkcvc,
      wvc,  Wkcvc + (size_t)D * DC,
      wo,   WoT);

  {
    dim3 g((2 * D + DC) / 128, M / 128);                   // (17, 32)
    gemm_fused3<<<g, 256, 0, stream>>>(Xb, Wbig, qsb, ksb, ckv, tq, tk, D);
  }
  {
    dim3 g(2 * D / 128, M / 128);                          // (16, 32)
    gemm_fused2<<<g, 256, 0, stream>>>(ckv, Wkcvc, ksb, vcb, DC);
  }

  dim3 tg(L / 64, NBH);
  vtrans_kernel<<<tg, 256, 0, stream>>>(vcb, vtb, L);

  dim3 fg(L / 128, NBH);                                   // (16, 32)
  flash15_kernel<<<fg, 512, 0, stream>>>(qsb, ksb, vtb, obuf, L);

  {
    dim3 g(D / 128, M / 64);                               // (8, 64)
    gemm_bt<64, float, false><<<g, 256, 0, stream>>>(
        obuf, WoT, (float*)d_out, M, D, D);
  }
}

// Round 9
// 218.505 us; speedup vs baseline: 1.4769x; 1.4769x over previous
//
#include <hip/hip_runtime.h>

typedef float          f32x4    __attribute__((ext_vector_type(4)));
typedef float          f32x2    __attribute__((ext_vector_type(2)));
typedef float          float8v  __attribute__((ext_vector_type(8)));
typedef unsigned short ushort8v __attribute__((ext_vector_type(8)));
typedef __bf16         bf16x8   __attribute__((ext_vector_type(8)));

__device__ __forceinline__ unsigned short f2b(float x) {
  union { __bf16 b; unsigned short u; } v;
  v.b = (__bf16)x;                       // hw v_cvt (RNE) on gfx950
  return v.u;
}
__device__ __forceinline__ float b2f(unsigned short h) {
  union { unsigned u; float f; } v; v.u = ((unsigned)h) << 16;
  return v.f;
}

// async global->LDS, 16B per lane; LDS dest = wave-uniform base + lane*16
__device__ __forceinline__ void g2lds16(const unsigned short* g,
                                        unsigned short* l) {
  __builtin_amdgcn_global_load_lds(
      (const __attribute__((address_space(1))) unsigned int*)g,
      (__attribute__((address_space(3))) unsigned int*)l, 16, 0, 0);
}

// ---------- prep kernel: cvt + 6 weight transposes + rope cos table ------
// Blocks [0, cvtb): f32->bf16 cvt, 8 elems/thread.
// Blocks [cvtb, cvtb+864): W(f32)[K][N] -> WT(bf16)[N][K] 64x64 tiles:
//   wqr(256) | wkr(256) | wkvc(32, N=128) | wkc(32, K=128) | wvc(32) | wo(256)
// Blocks [cvtb+864, cvtb+864+M/8): rope cos table
//   ctab[row*32+i] = (float2){cos(tq[row]*f_i), cos(tk[row]*f_i)}, i in [0,32)
__global__ __launch_bounds__(256) void prep_kernel(
    const float* __restrict__ X, unsigned short* __restrict__ Xb, int cvtb,
    int n8,
    const float* __restrict__ w0, unsigned short* __restrict__ t0,
    const float* __restrict__ w1, unsigned short* __restrict__ t1,
    const float* __restrict__ w2, unsigned short* __restrict__ t2,
    const float* __restrict__ w3, unsigned short* __restrict__ t3,
    const float* __restrict__ w4, unsigned short* __restrict__ t4,
    const float* __restrict__ w5, unsigned short* __restrict__ t5,
    const float* __restrict__ tq, const float* __restrict__ tk,
    f32x2* __restrict__ ctab) {
  __shared__ unsigned short T[64 * 72];
  const int tid = threadIdx.x;
  int blk = blockIdx.x;
  if (blk < cvtb) {
    int i = blk * 256 + tid;
    if (i >= n8) return;
    float8v v = reinterpret_cast<const float8v*>(X)[i];
    ushort8v h;
#pragma unroll
    for (int j = 0; j < 8; ++j) h[j] = f2b(v[j]);
    reinterpret_cast<ushort8v*>(Xb)[i] = h;
    return;
  }
  blk -= cvtb;
  if (blk >= 864) {
    // rope cos table
    int idx = (blk - 864) * 256 + tid;
    int row = idx >> 5, i = idx & 31;
    float f = exp2f(-(float)i * (13.287712379549449f / 32.f)); // 10000^(-i/32)
    f32x2 c;
    c[0] = cosf(tq[row] * f);
    c[1] = cosf(tk[row] * f);
    ctab[idx] = c;
    return;
  }
  const float* W; unsigned short* WT; int K, N, bx, by;
  if (blk < 256)      { W = w0; WT = t0; K = 1024; N = 1024; bx = blk & 15;         by = blk >> 4; }
  else if (blk < 512) { W = w1; WT = t1; K = 1024; N = 1024; bx = (blk - 256) & 15; by = (blk - 256) >> 4; }
  else if (blk < 544) { W = w2; WT = t2; K = 1024; N = 128;  bx = (blk - 512) & 1;  by = (blk - 512) >> 1; }
  else if (blk < 576) { W = w3; WT = t3; K = 128;  N = 1024; bx = (blk - 544) & 15; by = (blk - 544) >> 4; }
  else if (blk < 608) { W = w4; WT = t4; K = 128;  N = 1024; bx = (blk - 576) & 15; by = (blk - 576) >> 4; }
  else                { W = w5; WT = t5; K = 1024; N = 1024; bx = (blk - 608) & 15; by = (blk - 608) >> 4; }
  const int n0 = bx * 64, k0 = by * 64;
#pragma unroll
  for (int it = 0; it < 2; ++it) {
    int c = tid + it * 256;               // [0,512)
    int r = c >> 3, cc = c & 7;
    float8v v = *reinterpret_cast<const float8v*>(
        &W[(size_t)(k0 + r) * N + n0 + cc * 8]);
    ushort8v h;
#pragma unroll
    for (int j = 0; j < 8; ++j) h[j] = f2b(v[j]);
    *reinterpret_cast<ushort8v*>(&T[r * 72 + cc * 8]) = h;
  }
  __syncthreads();
#pragma unroll
  for (int it = 0; it < 2; ++it) {
    int c = tid + it * 256;
    int n = c >> 3, kc = c & 7;
    ushort8v y;
#pragma unroll
    for (int j = 0; j < 8; ++j) y[j] = T[(kc * 8 + j) * 72 + n];
    *reinterpret_cast<ushort8v*>(&WT[(size_t)(n0 + n) * K + k0 + kc * 8]) = y;
  }
}

// ---------------- generic gemm_bt (single-buffer) ----------------
template <int TM, typename CT, bool ACC>
__global__ __launch_bounds__(256) void gemm_bt(
    const unsigned short* __restrict__ A, const unsigned short* __restrict__ Bt,
    CT* __restrict__ C, int M, int N, int K) {
  __shared__ unsigned short As[TM * 64];
  __shared__ unsigned short Bs[128 * 64];
  const int tid = threadIdx.x;
  const int m0 = blockIdx.y * TM, n0 = blockIdx.x * 128;
  const int wave = tid >> 6, lane = tid & 63;
  const int wm = (wave >> 1) * (TM / 2), wn = (wave & 1) * 64;
  const int l16 = lane & 15, quad = lane >> 4;
  constexpr int MI = TM / 32;

  f32x4 acc[MI][4];
#pragma unroll
  for (int i = 0; i < MI; ++i)
#pragma unroll
    for (int j = 0; j < 4; ++j)
#pragma unroll
      for (int r = 0; r < 4; ++r) acc[i][j][r] = 0.f;

  for (int k0 = 0; k0 < K; k0 += 64) {
    __syncthreads();
#pragma unroll
    for (int it = 0; it < TM * 8 / 256; ++it) {
      int c = it * 256 + tid;
      int m = c >> 3, kc = (c & 7) ^ (m & 7);
      g2lds16(&A[(size_t)(m0 + m) * K + k0 + kc * 8], &As[c * 8]);
    }
#pragma unroll
    for (int it = 0; it < 4; ++it) {
      int c = it * 256 + tid;
      int n = c >> 3, kc = (c & 7) ^ (n & 7);
      g2lds16(&Bt[(size_t)(n0 + n) * K + k0 + kc * 8], &Bs[c * 8]);
    }
    __syncthreads();

#pragma unroll
    for (int ks = 0; ks < 2; ++ks) {
      bf16x8 af[MI], bfr[4];
#pragma unroll
      for (int mi = 0; mi < MI; ++mi) {
        int m = wm + mi * 16 + l16;
        af[mi] = *reinterpret_cast<const bf16x8*>(
            &As[(m * 8 + ((ks * 4 + quad) ^ (m & 7))) * 8]);
      }
#pragma unroll
      for (int ni = 0; ni < 4; ++ni) {
        int n = wn + ni * 16 + l16;
        bfr[ni] = *reinterpret_cast<const bf16x8*>(
            &Bs[(n * 8 + ((ks * 4 + quad) ^ (n & 7))) * 8]);
      }
#pragma unroll
      for (int mi = 0; mi < MI; ++mi)
#pragma unroll
        for (int ni = 0; ni < 4; ++ni)
          acc[mi][ni] = __builtin_amdgcn_mfma_f32_16x16x32_bf16(
              af[mi], bfr[ni], acc[mi][ni], 0, 0, 0);
    }
  }

#pragma unroll
  for (int mi = 0; mi < MI; ++mi)
#pragma unroll
    for (int ni = 0; ni < 4; ++ni) {
      int row = m0 + wm + mi * 16 + quad * 4;
      int col = n0 + wn + ni * 16 + l16;
#pragma unroll
      for (int r = 0; r < 4; ++r) {
        size_t idx = (size_t)(row + r) * N + col;
        float val = acc[mi][ni][r];
        if constexpr (sizeof(CT) == 2) {
          if constexpr (ACC) val += b2f(C[idx]);
          C[idx] = f2b(val);
        } else {
          if constexpr (ACC) val += C[idx];
          C[idx] = val;
        }
      }
    }
}

// -- fused GEMM #1 + rope: [q_r|k_r|c_kv] = X @ [wqr|wkr|wkvc]^T ----------
// Rope in epilogue via PRECOMPUTED cos table (no transcendentals here, so
// acc stays in VGPRs — R8's cosf-in-epilogue spilled acc to scratch and
// caused 557MB of phantom writes). Partner col^32 = acc[mi][np^2][r] in the
// same lane:
//   out[col]    = (v1*cq - v2*ck) * s
//   out[col+32] = (v2*cq + v1*ck) * s     (s = 0.125*log2e for q, 1 for k)
__global__ __launch_bounds__(256) void gemm_fused3(
    const unsigned short* __restrict__ A, const unsigned short* __restrict__ Bt,
    unsigned short* __restrict__ Cq, unsigned short* __restrict__ Ck,
    unsigned short* __restrict__ Cc, const f32x2* __restrict__ ctab, int K) {
  __shared__ unsigned short As[1024 * 8];
  __shared__ unsigned short Bs[1024 * 8];
  const int tid = threadIdx.x;
  const int m0 = blockIdx.y * 128, n0 = blockIdx.x * 128;
  const int wave = tid >> 6, lane = tid & 63;
  const int wm = (wave >> 1) * 64, wn = (wave & 1) * 64;
  const int l16 = lane & 15, quad = lane >> 4;

  f32x4 acc[4][4];
#pragma unroll
  for (int i = 0; i < 4; ++i)
#pragma unroll
    for (int j = 0; j < 4; ++j)
#pragma unroll
      for (int r = 0; r < 4; ++r) acc[i][j][r] = 0.f;

  for (int k0 = 0; k0 < K; k0 += 64) {
    __syncthreads();
#pragma unroll
    for (int it = 0; it < 4; ++it) {
      int c = it * 256 + tid;
      int m = c >> 3, kc = (c & 7) ^ (m & 7);
      g2lds16(&A[(size_t)(m0 + m) * K + k0 + kc * 8], &As[c * 8]);
    }
#pragma unroll
    for (int it = 0; it < 4; ++it) {
      int c = it * 256 + tid;
      int n = c >> 3, kc = (c & 7) ^ (n & 7);
      g2lds16(&Bt[(size_t)(n0 + n) * K + k0 + kc * 8], &Bs[c * 8]);
    }
    __syncthreads();

#pragma unroll
    for (int ks = 0; ks < 2; ++ks) {
      bf16x8 af[4], bfr[4];
#pragma unroll
      for (int mi = 0; mi < 4; ++mi) {
        int m = wm + mi * 16 + l16;
        af[mi] = *reinterpret_cast<const bf16x8*>(
            &As[(m * 8 + ((ks * 4 + quad) ^ (m & 7))) * 8]);
      }
#pragma unroll
      for (int ni = 0; ni < 4; ++ni) {
        int n = wn + ni * 16 + l16;
        bfr[ni] = *reinterpret_cast<const bf16x8*>(
            &Bs[(n * 8 + ((ks * 4 + quad) ^ (n & 7))) * 8]);
      }
#pragma unroll
      for (int mi = 0; mi < 4; ++mi)
#pragma unroll
        for (int ni = 0; ni < 4; ++ni)
          acc[mi][ni] = __builtin_amdgcn_mfma_f32_16x16x32_bf16(
              af[mi], bfr[ni], acc[mi][ni], 0, 0, 0);
    }
  }

  if (n0 < 2048) {
    // rope path (q or k): cq/ck from table, pure FMA epilogue
    const bool isq = (n0 < 1024);
    unsigned short* dst = isq ? Cq : Ck;
    const int cb = isq ? 0 : 1024;
    const float s = isq ? 0.18033688011112042f : 1.0f;  // 0.125*log2(e) | 1
#pragma unroll
    for (int mi = 0; mi < 4; ++mi)
#pragma unroll
      for (int r = 0; r < 4; ++r) {
        int row = m0 + wm + mi * 16 + quad * 4 + r;
        const f32x2* crow = &ctab[(size_t)row * 32];
#pragma unroll
        for (int np = 0; np < 2; ++np) {
          f32x2 cc = crow[np * 16 + l16];        // {cq, ck}
          float v1 = acc[mi][np][r], v2 = acc[mi][np + 2][r];
          int col = n0 - cb + wn + np * 16 + l16;
          dst[(size_t)row * 1024 + col]      = f2b((v1 * cc[0] - v2 * cc[1]) * s);
          dst[(size_t)row * 1024 + col + 32] = f2b((v2 * cc[0] + v1 * cc[1]) * s);
        }
      }
  } else {
    // c_kv plain store
#pragma unroll
    for (int mi = 0; mi < 4; ++mi)
#pragma unroll
      for (int ni = 0; ni < 4; ++ni) {
        int row = m0 + wm + mi * 16 + quad * 4;
        int col = n0 - 2048 + wn + ni * 16 + l16;
#pragma unroll
        for (int r = 0; r < 4; ++r)
          Cc[(size_t)(row + r) * 128 + col] = f2b(acc[mi][ni][r]);
      }
  }
}

// ------- fused GEMM #2: [k_c(acc->ksb) | v_c] = ckv @ [wkc|wvc]^T -------
__global__ __launch_bounds__(256) void gemm_fused2(
    const unsigned short* __restrict__ A, const unsigned short* __restrict__ Bt,
    unsigned short* __restrict__ Ck, unsigned short* __restrict__ Cv, int K) {
  __shared__ unsigned short As[1024 * 8];
  __shared__ unsigned short Bs[1024 * 8];
  const int tid = threadIdx.x;
  const int m0 = blockIdx.y * 128, n0 = blockIdx.x * 128;
  const int wave = tid >> 6, lane = tid & 63;
  const int wm = (wave >> 1) * 64, wn = (wave & 1) * 64;
  const int l16 = lane & 15, quad = lane >> 4;

  f32x4 acc[4][4];
#pragma unroll
  for (int i = 0; i < 4; ++i)
#pragma unroll
    for (int j = 0; j < 4; ++j)
#pragma unroll
      for (int r = 0; r < 4; ++r) acc[i][j][r] = 0.f;

  for (int k0 = 0; k0 < K; k0 += 64) {
    __syncthreads();
#pragma unroll
    for (int it = 0; it < 4; ++it) {
      int c = it * 256 + tid;
      int m = c >> 3, kc = (c & 7) ^ (m & 7);
      g2lds16(&A[(size_t)(m0 + m) * K + k0 + kc * 8], &As[c * 8]);
    }
#pragma unroll
    for (int it = 0; it < 4; ++it) {
      int c = it * 256 + tid;
      int n = c >> 3, kc = (c & 7) ^ (n & 7);
      g2lds16(&Bt[(size_t)(n0 + n) * K + k0 + kc * 8], &Bs[c * 8]);
    }
    __syncthreads();

#pragma unroll
    for (int ks = 0; ks < 2; ++ks) {
      bf16x8 af[4], bfr[4];
#pragma unroll
      for (int mi = 0; mi < 4; ++mi) {
        int m = wm + mi * 16 + l16;
        af[mi] = *reinterpret_cast<const bf16x8*>(
            &As[(m * 8 + ((ks * 4 + quad) ^ (m & 7))) * 8]);
      }
#pragma unroll
      for (int ni = 0; ni < 4; ++ni) {
        int n = wn + ni * 16 + l16;
        bfr[ni] = *reinterpret_cast<const bf16x8*>(
            &Bs[(n * 8 + ((ks * 4 + quad) ^ (n & 7))) * 8]);
      }
#pragma unroll
      for (int mi = 0; mi < 4; ++mi)
#pragma unroll
        for (int ni = 0; ni < 4; ++ni)
          acc[mi][ni] = __builtin_amdgcn_mfma_f32_16x16x32_bf16(
              af[mi], bfr[ni], acc[mi][ni], 0, 0, 0);
    }
  }

  const bool first = (n0 < 1024);
  unsigned short* dst = first ? Ck : Cv;
  int cb = first ? 0 : 1024;
#pragma unroll
  for (int mi = 0; mi < 4; ++mi)
#pragma unroll
    for (int ni = 0; ni < 4; ++ni) {
      int row = m0 + wm + mi * 16 + quad * 4;
      int col = n0 - cb + wn + ni * 16 + l16;
#pragma unroll
      for (int r = 0; r < 4; ++r) {
        size_t idx = (size_t)(row + r) * 1024 + col;
        float val = acc[mi][ni][r];
        if (first) val += b2f(dst[idx]);   // accumulate onto rope'd k_r
        dst[idx] = f2b(val);
      }
    }
}

// ------ V transpose + key-permute: [b,l,h,d] -> Vt[b,h,d,sigma^-1(l)] ------
// sigma^-1: s = [k5 k3 k2 k4 k1 k0] (bits 5..0). Output position group g
// (8 consecutive s = g*8+e) gathers keys
//   key(g,e) = (g>>2)<<5 | (e>>2)<<4 | ((g>>1)&1)<<3 | (g&1)<<2 | (e&3)
// so each 16B store stays fully vectorized (b128).
__global__ __launch_bounds__(256) void vtrans_kernel(
    const unsigned short* __restrict__ v, unsigned short* __restrict__ vt,
    int L) {
  __shared__ unsigned short T[64 * 72];
  const int tid = threadIdx.x;
  const int l0 = blockIdx.x * 64, bh = blockIdx.y;
  const size_t inbase = ((size_t)(bh >> 4) * L) * 1024 + (bh & 15) * 64;
  const size_t outbase = (size_t)bh * 64 * L;
#pragma unroll
  for (int it = 0; it < 2; ++it) {
    int c = tid + it * 256;               // [0,512)
    int l = c >> 3, dc = c & 7;
    ushort8v x = *reinterpret_cast<const ushort8v*>(
        &v[inbase + (size_t)(l0 + l) * 1024 + dc * 8]);
    *reinterpret_cast<ushort8v*>(&T[l * 72 + dc * 8]) = x;
  }
  __syncthreads();
#pragma unroll
  for (int it = 0; it < 2; ++it) {
    int c = tid + it * 256;
    int d = c >> 3, g = c & 7;
    ushort8v y;
#pragma unroll
    for (int e = 0; e < 8; ++e) {
      int k = ((g >> 2) << 5) | ((e >> 2) << 4) | (((g >> 1) & 1) << 3) |
              ((g & 1) << 2) | (e & 3);
      y[e] = T[k * 72 + d];
    }
    *reinterpret_cast<ushort8v*>(&vt[outbase + (size_t)d * L + l0 + g * 8]) = y;
  }
}

// ---------- flash v15: 8 waves, 512 thr, in-block KV-split ----------
// waves 0-3 process KV [0,L/2), waves 4-7 KV [L/2,L), same 128 q rows.
// No max-subtraction -> O and l additive over key ranges: half-1 waves
// write (oacc,lacc) to LDS once at the end; half-0 adds, normalizes, stores.
__global__ __launch_bounds__(512) void flash15_kernel(
    const unsigned short* __restrict__ qs, const unsigned short* __restrict__ ks,
    const unsigned short* __restrict__ vt, unsigned short* __restrict__ o,
    int L) {
  // [kv={K,V}][half][dbuf][64x64 swizzled]  = 64KB total
  __shared__ unsigned short KV[2][2][2][512 * 8];
  const int tid = threadIdx.x;
  const int wave = tid >> 6, lane = tid & 63;
  const int half = wave >> 2;                  // KV half this wave works on
  const int l16 = lane & 15, quad = lane >> 4;
  const int bh = blockIdx.y;                   // b*16 + h
  const int qb = blockIdx.x * 128 + (wave & 3) * 32;  // this wave's 32 q rows
  const size_t base = ((size_t)(bh >> 4) * L) * 1024 + (bh & 15) * 64;
  const size_t vtbase = (size_t)bh * 64 * L;
  const int kvoff = half * (L >> 1);           // key offset of this half
  const int sid = tid & 255;                   // staging lane within half

  bf16x8 aq[2][2];
#pragma unroll
  for (int mt = 0; mt < 2; ++mt) {
    size_t qrow = base + (size_t)(qb + mt * 16 + l16) * 1024;
    aq[mt][0] = *reinterpret_cast<const bf16x8*>(&qs[qrow + quad * 8]);
    aq[mt][1] = *reinterpret_cast<const bf16x8*>(&qs[qrow + 32 + quad * 8]);
  }

  ushort8v onesu;
#pragma unroll
  for (int j = 0; j < 8; ++j) onesu[j] = 0x3F80;  // bf16 1.0
  bf16x8 ones = *reinterpret_cast<bf16x8*>(&onesu);

  f32x4 oacc[2][4];
  f32x4 lacc[2];
#pragma unroll
  for (int mt = 0; mt < 2; ++mt) {
#pragma unroll
    for (int r = 0; r < 4; ++r) lacc[mt][r] = 0.f;
#pragma unroll
    for (int nt = 0; nt < 4; ++nt)
#pragma unroll
      for (int r = 0; r < 4; ++r) oacc[mt][nt][r] = 0.f;
  }

  const int T = L / 128;   // 16 tiles per half
  // prologue: each half's 256 threads stage that half's tile 0
#pragma unroll
  for (int it = 0; it < 2; ++it) {
    int c = it * 256 + sid;                    // [0,512)
    int key = c >> 3, dc = (c & 7) ^ (key & 7);
    g2lds16(&ks[base + (size_t)(kvoff + key) * 1024 + dc * 8],
            &KV[0][half][0][c * 8]);
  }
#pragma unroll
  for (int it = 0; it < 2; ++it) {
    int c = it * 256 + sid;
    int d = c >> 3, kc = (c & 7) ^ (d & 7);
    g2lds16(&vt[vtbase + (size_t)d * L + kvoff + kc * 8],
            &KV[1][half][0][c * 8]);
  }

  for (int t = 0; t < T; ++t) {
    __syncthreads();   // drains stage(t); prior-buf readers done
    if (t + 1 < T) {
      int k0 = kvoff + (t + 1) * 64, nb = (t + 1) & 1;
#pragma unroll
      for (int it = 0; it < 2; ++it) {
        int c = it * 256 + sid;
        int key = c >> 3, dc = (c & 7) ^ (key & 7);
        g2lds16(&ks[base + (size_t)(k0 + key) * 1024 + dc * 8],
                &KV[0][half][nb][c * 8]);
      }
#pragma unroll
      for (int it = 0; it < 2; ++it) {
        int c = it * 256 + sid;
        int d = c >> 3, kc = (c & 7) ^ (d & 7);
        g2lds16(&vt[vtbase + (size_t)d * L + k0 + kc * 8],
                &KV[1][half][nb][c * 8]);
      }
    }
    const int cb = t & 1;
    const unsigned short* Ks = &KV[0][half][cb][0];
    const unsigned short* Vs = &KV[1][half][cb][0];

    // S^T = K Q^T for BOTH m-tiles; K fragments read once.
    f32x4 st[2][4];
#pragma unroll
    for (int nt = 0; nt < 4; ++nt) {
      int key = nt * 16 + l16;
      int dc0 = quad ^ (key & 7);
      int dc1 = (4 + quad) ^ (key & 7);
      bf16x8 bk0 = *reinterpret_cast<const bf16x8*>(&Ks[(key * 8 + dc0) * 8]);
      bf16x8 bk1 = *reinterpret_cast<const bf16x8*>(&Ks[(key * 8 + dc1) * 8]);
#pragma unroll
      for (int mt = 0; mt < 2; ++mt) {
        f32x4 z; z[0] = z[1] = z[2] = z[3] = 0.f;
        z = __builtin_amdgcn_mfma_f32_16x16x32_bf16(bk0, aq[mt][0], z, 0, 0, 0);
        z = __builtin_amdgcn_mfma_f32_16x16x32_bf16(bk1, aq[mt][1], z, 0, 0, 0);
        st[mt][nt] = z;
      }
    }

    // exp2 -> ap frags by pure register renaming (key-permutation sigma)
    bf16x8 ap[2][2];
#pragma unroll
    for (int mt = 0; mt < 2; ++mt) {
#pragma unroll
      for (int hf = 0; hf < 2; ++hf)
#pragma unroll
        for (int w = 0; w < 4; ++w) {
          int nt = 2 * hf + (w >> 1), p = w & 1;
          ap[mt][hf][2 * w] =
              (__bf16)__builtin_amdgcn_exp2f(st[mt][nt][2 * p]);
          ap[mt][hf][2 * w + 1] =
              (__bf16)__builtin_amdgcn_exp2f(st[mt][nt][2 * p + 1]);
        }
      lacc[mt] = __builtin_amdgcn_mfma_f32_16x16x32_bf16(ap[mt][0], ones,
                                                         lacc[mt], 0, 0, 0);
      lacc[mt] = __builtin_amdgcn_mfma_f32_16x16x32_bf16(ap[mt][1], ones,
                                                         lacc[mt], 0, 0, 0);
    }

    // O += P V (V fragments read once, reused by both m-tiles)
#pragma unroll
    for (int nt = 0; nt < 4; ++nt) {
      int d = nt * 16 + l16;
#pragma unroll
      for (int hf = 0; hf < 2; ++hf) {
        int kc = (hf * 4 + quad) ^ (d & 7);
        bf16x8 bv = *reinterpret_cast<const bf16x8*>(&Vs[(d * 8 + kc) * 8]);
#pragma unroll
        for (int mt = 0; mt < 2; ++mt)
          oacc[mt][nt] = __builtin_amdgcn_mfma_f32_16x16x32_bf16(
              ap[mt][hf], bv, oacc[mt][nt], 0, 0, 0);
      }
    }
  }

  // ---- combine halves in LDS (O and l are additive; no max used) ----
  __syncthreads();                 // all K/V reads done; LDS reusable
  float* cbuf = (float*)&KV[0][0][0][0];   // 45056B needed <= 64KB
  if (half == 1) {
    int slot = ((wave - 4) * 64 + lane) * 44;   // stride 44 f32 (16B-aligned)
#pragma unroll
    for (int mt = 0; mt < 2; ++mt) {
#pragma unroll
      for (int nt = 0; nt < 4; ++nt)
        *reinterpret_cast<f32x4*>(&cbuf[slot + (mt * 4 + nt) * 4]) =
            oacc[mt][nt];
      *reinterpret_cast<f32x4*>(&cbuf[slot + 32 + mt * 4]) = lacc[mt];
    }
  }
  __syncthreads();
  if (half == 0) {
    int slot = (wave * 64 + lane) * 44;
#pragma unroll
    for (int mt = 0; mt < 2; ++mt) {
#pragma unroll
      for (int nt = 0; nt < 4; ++nt) {
        f32x4 ov = *reinterpret_cast<const f32x4*>(
            &cbuf[slot + (mt * 4 + nt) * 4]);
#pragma unroll
        for (int r = 0; r < 4; ++r) oacc[mt][nt][r] += ov[r];
      }
      f32x4 lv = *reinterpret_cast<const f32x4*>(&cbuf[slot + 32 + mt * 4]);
#pragma unroll
      for (int r = 0; r < 4; ++r) lacc[mt][r] += lv[r];
    }
#pragma unroll
    for (int mt = 0; mt < 2; ++mt)
#pragma unroll
      for (int r = 0; r < 4; ++r) {
        float inv = __builtin_amdgcn_rcpf(lacc[mt][r]);
        int q = qb + mt * 16 + quad * 4 + r;
#pragma unroll
        for (int nt = 0; nt < 4; ++nt)
          o[base + (size_t)q * 1024 + nt * 16 + l16] =
              f2b(oacc[mt][nt][r] * inv);
      }
  }
}

// ---------------- driver ----------------
extern "C" void kernel_launch(void* const* d_in, const int* in_sizes, int n_in,
                              void* d_out, int out_size, void* d_ws, size_t ws_size,
                              hipStream_t stream) {
  const float* X    = (const float*)d_in[0];
  const float* tq   = (const float*)d_in[1];
  const float* tk   = (const float*)d_in[2];
  const float* wkvc = (const float*)d_in[3];
  const float* wkc  = (const float*)d_in[4];
  const float* wvc  = (const float*)d_in[5];
  const float* wqr  = (const float*)d_in[6];
  const float* wkr  = (const float*)d_in[7];
  const float* wo   = (const float*)d_in[8];

  const int D = 1024, DC = 128, L = 2048;
  const int M = in_sizes[0] / D;       // B*L
  const int B = M / L;
  const int NBH = B * 16;
  (void)n_in; (void)out_size; (void)ws_size;

  unsigned short* p = (unsigned short*)d_ws;
  auto take = [&](size_t n) { unsigned short* r = p; p += n; return r; };
  unsigned short* Xb    = take((size_t)M * D);
  unsigned short* qsb   = take((size_t)M * D);
  unsigned short* ksb   = take((size_t)M * D);
  unsigned short* vcb   = take((size_t)M * D);
  unsigned short* ckv   = take((size_t)M * DC);
  unsigned short* Wbig  = take((size_t)(2 * D + DC) * D);   // [wqr|wkr|wkvc]^T
  unsigned short* Wkcvc = take((size_t)(2 * D) * DC);       // [wkc|wvc]^T
  unsigned short* WoT   = take((size_t)D * D);
  f32x2* ctab = (f32x2*)take((size_t)M * 32 * 4);           // M*32 float2
  unsigned short* vtb   = Xb;   // Xb dead after fused3 gemm
  unsigned short* obuf  = vcb;  // vcb dead after vtrans; flash O lands here

  // prep: cvt + all 6 weight transposes + rope cos table in ONE launch
  const int n8 = M * D / 8;
  const int cvtb = (n8 + 255) / 256;
  const int ropeb = M / 8;             // M*32 threads / 256
  prep_kernel<<<cvtb + 864 + ropeb, 256, 0, stream>>>(
      X, Xb, cvtb, n8,
      wqr,  Wbig,
      wkr,  Wbig + (size_t)D * D,
      wkvc, Wbig + (size_t)2 * D * D,
      wkc,  Wkcvc,
      wvc,  Wkcvc + (size_t)D * DC,
      wo,   WoT,
      tq, tk, ctab);

  {
    dim3 g((2 * D + DC) / 128, M / 128);                   // (17, 32)
    gemm_fused3<<<g, 256, 0, stream>>>(Xb, Wbig, qsb, ksb, ckv, ctab, D);
  }
  {
    dim3 g(2 * D / 128, M / 128);                          // (16, 32)
    gemm_fused2<<<g, 256, 0, stream>>>(ckv, Wkcvc, ksb, vcb, DC);
  }

  dim3 tg(L / 64, NBH);
  vtrans_kernel<<<tg, 256, 0, stream>>>(vcb, vtb, L);

  dim3 fg(L / 128, NBH);                                   // (16, 32)
  flash15_kernel<<<fg, 512, 0, stream>>>(qsb, ksb, vtb, obuf, L);

  {
    dim3 g(D / 128, M / 64);                               // (8, 64)
    gemm_bt<64, float, false><<<g, 256, 0, stream>>>(
        obuf, WoT, (float*)d_out, M, D, D);
  }
}

// Round 10
// 199.419 us; speedup vs baseline: 1.6183x; 1.0957x over previous
//
#include <hip/hip_runtime.h>

typedef float          f32x4    __attribute__((ext_vector_type(4)));
typedef float          f32x2    __attribute__((ext_vector_type(2)));
typedef float          float8v  __attribute__((ext_vector_type(8)));
typedef unsigned short ushort8v __attribute__((ext_vector_type(8)));
typedef unsigned short ushort4v __attribute__((ext_vector_type(4)));
typedef __bf16         bf16x8   __attribute__((ext_vector_type(8)));

__device__ __forceinline__ unsigned short f2b(float x) {
  union { __bf16 b; unsigned short u; } v;
  v.b = (__bf16)x;                       // hw v_cvt (RNE) on gfx950
  return v.u;
}
__device__ __forceinline__ float b2f(unsigned short h) {
  union { unsigned u; float f; } v; v.u = ((unsigned)h) << 16;
  return v.f;
}

// async global->LDS, 16B per lane; LDS dest = wave-uniform base + lane*16
__device__ __forceinline__ void g2lds16(const unsigned short* g,
                                        unsigned short* l) {
  __builtin_amdgcn_global_load_lds(
      (const __attribute__((address_space(1))) unsigned int*)g,
      (__attribute__((address_space(3))) unsigned int*)l, 16, 0, 0);
}

// ---------- prep kernel: cvt + 6 weight transposes + rope cos table ------
// Blocks [0, cvtb): f32->bf16 cvt, 8 elems/thread.
// Blocks [cvtb, cvtb+864): W(f32)[K][N] -> WT(bf16)[N][K] 64x64 tiles:
//   wqr(256) | wkr(256) | wkvc(32, N=128) | wkc(32, K=128) | wvc(32) | wo(256)
// Blocks [cvtb+864, cvtb+864+M/8): rope cos table
//   ctab[row*32+i] = (float2){cos(tq[row]*f_i), cos(tk[row]*f_i)}, i in [0,32)
__global__ __launch_bounds__(256) void prep_kernel(
    const float* __restrict__ X, unsigned short* __restrict__ Xb, int cvtb,
    int n8,
    const float* __restrict__ w0, unsigned short* __restrict__ t0,
    const float* __restrict__ w1, unsigned short* __restrict__ t1,
    const float* __restrict__ w2, unsigned short* __restrict__ t2,
    const float* __restrict__ w3, unsigned short* __restrict__ t3,
    const float* __restrict__ w4, unsigned short* __restrict__ t4,
    const float* __restrict__ w5, unsigned short* __restrict__ t5,
    const float* __restrict__ tq, const float* __restrict__ tk,
    f32x2* __restrict__ ctab) {
  __shared__ unsigned short T[64 * 72];
  const int tid = threadIdx.x;
  int blk = blockIdx.x;
  if (blk < cvtb) {
    int i = blk * 256 + tid;
    if (i >= n8) return;
    float8v v = reinterpret_cast<const float8v*>(X)[i];
    ushort8v h;
#pragma unroll
    for (int j = 0; j < 8; ++j) h[j] = f2b(v[j]);
    reinterpret_cast<ushort8v*>(Xb)[i] = h;
    return;
  }
  blk -= cvtb;
  if (blk >= 864) {
    // rope cos table
    int idx = (blk - 864) * 256 + tid;
    int row = idx >> 5, i = idx & 31;
    float f = exp2f(-(float)i * (13.287712379549449f / 32.f)); // 10000^(-i/32)
    f32x2 c;
    c[0] = cosf(tq[row] * f);
    c[1] = cosf(tk[row] * f);
    ctab[idx] = c;
    return;
  }
  const float* W; unsigned short* WT; int K, N, bx, by;
  if (blk < 256)      { W = w0; WT = t0; K = 1024; N = 1024; bx = blk & 15;         by = blk >> 4; }
  else if (blk < 512) { W = w1; WT = t1; K = 1024; N = 1024; bx = (blk - 256) & 15; by = (blk - 256) >> 4; }
  else if (blk < 544) { W = w2; WT = t2; K = 1024; N = 128;  bx = (blk - 512) & 1;  by = (blk - 512) >> 1; }
  else if (blk < 576) { W = w3; WT = t3; K = 128;  N = 1024; bx = (blk - 544) & 15; by = (blk - 544) >> 4; }
  else if (blk < 608) { W = w4; WT = t4; K = 128;  N = 1024; bx = (blk - 576) & 15; by = (blk - 576) >> 4; }
  else                { W = w5; WT = t5; K = 1024; N = 1024; bx = (blk - 608) & 15; by = (blk - 608) >> 4; }
  const int n0 = bx * 64, k0 = by * 64;
#pragma unroll
  for (int it = 0; it < 2; ++it) {
    int c = tid + it * 256;               // [0,512)
    int r = c >> 3, cc = c & 7;
    float8v v = *reinterpret_cast<const float8v*>(
        &W[(size_t)(k0 + r) * N + n0 + cc * 8]);
    ushort8v h;
#pragma unroll
    for (int j = 0; j < 8; ++j) h[j] = f2b(v[j]);
    *reinterpret_cast<ushort8v*>(&T[r * 72 + cc * 8]) = h;
  }
  __syncthreads();
#pragma unroll
  for (int it = 0; it < 2; ++it) {
    int c = tid + it * 256;
    int n = c >> 3, kc = c & 7;
    ushort8v y;
#pragma unroll
    for (int j = 0; j < 8; ++j) y[j] = T[(kc * 8 + j) * 72 + n];
    *reinterpret_cast<ushort8v*>(&WT[(size_t)(n0 + n) * K + k0 + kc * 8]) = y;
  }
}

// ------------ generic gemm_bt (single-buffer, XCD-swizzled 1D grid) -------
// grid = (N/128)*(M/TM) blocks, must be divisible by 8. Chunked XCD swizzle
// shrinks each XCD's L2 working set (consecutive chunk -> few A panels + B).
template <int TM, typename CT, bool ACC>
__global__ __launch_bounds__(256) void gemm_bt(
    const unsigned short* __restrict__ A, const unsigned short* __restrict__ Bt,
    CT* __restrict__ C, int M, int N, int K) {
  __shared__ unsigned short As[TM * 64];
  __shared__ unsigned short Bs[128 * 64];
  const int tid = threadIdx.x;
  const int id = blockIdx.x, cpx = gridDim.x >> 3;
  const int swz = (id & 7) * cpx + (id >> 3);
  const int nwx = N / 128;
  const int m0 = (swz / nwx) * TM, n0 = (swz % nwx) * 128;
  const int wave = tid >> 6, lane = tid & 63;
  const int wm = (wave >> 1) * (TM / 2), wn = (wave & 1) * 64;
  const int l16 = lane & 15, quad = lane >> 4;
  constexpr int MI = TM / 32;

  f32x4 acc[MI][4];
#pragma unroll
  for (int i = 0; i < MI; ++i)
#pragma unroll
    for (int j = 0; j < 4; ++j)
#pragma unroll
      for (int r = 0; r < 4; ++r) acc[i][j][r] = 0.f;

  for (int k0 = 0; k0 < K; k0 += 64) {
    __syncthreads();
#pragma unroll
    for (int it = 0; it < TM * 8 / 256; ++it) {
      int c = it * 256 + tid;
      int m = c >> 3, kc = (c & 7) ^ (m & 7);
      g2lds16(&A[(size_t)(m0 + m) * K + k0 + kc * 8], &As[c * 8]);
    }
#pragma unroll
    for (int it = 0; it < 4; ++it) {
      int c = it * 256 + tid;
      int n = c >> 3, kc = (c & 7) ^ (n & 7);
      g2lds16(&Bt[(size_t)(n0 + n) * K + k0 + kc * 8], &Bs[c * 8]);
    }
    __syncthreads();

#pragma unroll
    for (int ks = 0; ks < 2; ++ks) {
      bf16x8 af[MI], bfr[4];
#pragma unroll
      for (int mi = 0; mi < MI; ++mi) {
        int m = wm + mi * 16 + l16;
        af[mi] = *reinterpret_cast<const bf16x8*>(
            &As[(m * 8 + ((ks * 4 + quad) ^ (m & 7))) * 8]);
      }
#pragma unroll
      for (int ni = 0; ni < 4; ++ni) {
        int n = wn + ni * 16 + l16;
        bfr[ni] = *reinterpret_cast<const bf16x8*>(
            &Bs[(n * 8 + ((ks * 4 + quad) ^ (n & 7))) * 8]);
      }
#pragma unroll
      for (int mi = 0; mi < MI; ++mi)
#pragma unroll
        for (int ni = 0; ni < 4; ++ni)
          acc[mi][ni] = __builtin_amdgcn_mfma_f32_16x16x32_bf16(
              af[mi], bfr[ni], acc[mi][ni], 0, 0, 0);
    }
  }

#pragma unroll
  for (int mi = 0; mi < MI; ++mi)
#pragma unroll
    for (int ni = 0; ni < 4; ++ni) {
      int row = m0 + wm + mi * 16 + quad * 4;
      int col = n0 + wn + ni * 16 + l16;
#pragma unroll
      for (int r = 0; r < 4; ++r) {
        size_t idx = (size_t)(row + r) * N + col;
        float val = acc[mi][ni][r];
        if constexpr (sizeof(CT) == 2) {
          if constexpr (ACC) val += b2f(C[idx]);
          C[idx] = f2b(val);
        } else {
          if constexpr (ACC) val += C[idx];
          C[idx] = val;
        }
      }
    }
}

// -- fused GEMM #1 + rope: [q_r|k_r|c_kv] = X @ [wqr|wkr|wkvc]^T ----------
// Rope in epilogue via PRECOMPUTED cos table (R8 lesson: transcendentals in
// the epilogue spill acc to scratch). 1D grid (544 = 8*68) with chunked XCD
// swizzle for L2 locality. Partner col^32 = acc[mi][np^2][r] in-lane:
//   out[col]    = (v1*cq - v2*ck) * s
//   out[col+32] = (v2*cq + v1*ck) * s     (s = 0.125*log2e for q, 1 for k)
__global__ __launch_bounds__(256) void gemm_fused3(
    const unsigned short* __restrict__ A, const unsigned short* __restrict__ Bt,
    unsigned short* __restrict__ Cq, unsigned short* __restrict__ Ck,
    unsigned short* __restrict__ Cc, const f32x2* __restrict__ ctab, int K) {
  __shared__ unsigned short As[1024 * 8];
  __shared__ unsigned short Bs[1024 * 8];
  const int tid = threadIdx.x;
  const int id = blockIdx.x;
  const int swz = (id & 7) * 68 + (id >> 3);          // 544 = 8*68 bijective
  const int m0 = (swz / 17) * 128, n0 = (swz % 17) * 128;
  const int wave = tid >> 6, lane = tid & 63;
  const int wm = (wave >> 1) * 64, wn = (wave & 1) * 64;
  const int l16 = lane & 15, quad = lane >> 4;

  f32x4 acc[4][4];
#pragma unroll
  for (int i = 0; i < 4; ++i)
#pragma unroll
    for (int j = 0; j < 4; ++j)
#pragma unroll
      for (int r = 0; r < 4; ++r) acc[i][j][r] = 0.f;

  for (int k0 = 0; k0 < K; k0 += 64) {
    __syncthreads();
#pragma unroll
    for (int it = 0; it < 4; ++it) {
      int c = it * 256 + tid;
      int m = c >> 3, kc = (c & 7) ^ (m & 7);
      g2lds16(&A[(size_t)(m0 + m) * K + k0 + kc * 8], &As[c * 8]);
    }
#pragma unroll
    for (int it = 0; it < 4; ++it) {
      int c = it * 256 + tid;
      int n = c >> 3, kc = (c & 7) ^ (n & 7);
      g2lds16(&Bt[(size_t)(n0 + n) * K + k0 + kc * 8], &Bs[c * 8]);
    }
    __syncthreads();

#pragma unroll
    for (int ks = 0; ks < 2; ++ks) {
      bf16x8 af[4], bfr[4];
#pragma unroll
      for (int mi = 0; mi < 4; ++mi) {
        int m = wm + mi * 16 + l16;
        af[mi] = *reinterpret_cast<const bf16x8*>(
            &As[(m * 8 + ((ks * 4 + quad) ^ (m & 7))) * 8]);
      }
#pragma unroll
      for (int ni = 0; ni < 4; ++ni) {
        int n = wn + ni * 16 + l16;
        bfr[ni] = *reinterpret_cast<const bf16x8*>(
            &Bs[(n * 8 + ((ks * 4 + quad) ^ (n & 7))) * 8]);
      }
#pragma unroll
      for (int mi = 0; mi < 4; ++mi)
#pragma unroll
        for (int ni = 0; ni < 4; ++ni)
          acc[mi][ni] = __builtin_amdgcn_mfma_f32_16x16x32_bf16(
              af[mi], bfr[ni], acc[mi][ni], 0, 0, 0);
    }
  }

  if (n0 < 2048) {
    // rope path (q or k): cq/ck from table, pure FMA epilogue
    const bool isq = (n0 < 1024);
    unsigned short* dst = isq ? Cq : Ck;
    const int cb = isq ? 0 : 1024;
    const float s = isq ? 0.18033688011112042f : 1.0f;  // 0.125*log2(e) | 1
#pragma unroll
    for (int mi = 0; mi < 4; ++mi)
#pragma unroll
      for (int r = 0; r < 4; ++r) {
        int row = m0 + wm + mi * 16 + quad * 4 + r;
        const f32x2* crow = &ctab[(size_t)row * 32];
#pragma unroll
        for (int np = 0; np < 2; ++np) {
          f32x2 cc = crow[np * 16 + l16];        // {cq, ck}
          float v1 = acc[mi][np][r], v2 = acc[mi][np + 2][r];
          int col = n0 - cb + wn + np * 16 + l16;
          dst[(size_t)row * 1024 + col]      = f2b((v1 * cc[0] - v2 * cc[1]) * s);
          dst[(size_t)row * 1024 + col + 32] = f2b((v2 * cc[0] + v1 * cc[1]) * s);
        }
      }
  } else {
    // c_kv plain store
#pragma unroll
    for (int mi = 0; mi < 4; ++mi)
#pragma unroll
      for (int ni = 0; ni < 4; ++ni) {
        int row = m0 + wm + mi * 16 + quad * 4;
        int col = n0 - 2048 + wn + ni * 16 + l16;
#pragma unroll
        for (int r = 0; r < 4; ++r)
          Cc[(size_t)(row + r) * 128 + col] = f2b(acc[mi][ni][r]);
      }
  }
}

// ------- fused GEMM #2: [k_c(acc->ksb) | v_c -> Vt direct] ---------------
// k_c accumulates onto rope'd k_r in ksb (unchanged). v_c is stored
// DIRECTLY into the sigma^-1-permuted Vt[b,h,d,l'] layout, eliminating the
// vtrans kernel. sigma^-1: l' = [k5 k3 k2 k4 k1 k0]; each lane's 4
// consecutive rows (r=0..3, row%4==0 -> k1k0=r) map to 4 consecutive l',
// so each (mi,ni) is one aligned 8B (b64) store. The 4 quads + mi pairs of
// one l16 fill complete 64B lines -> L2 merges, no HBM write amplification.
__global__ __launch_bounds__(256) void gemm_fused2(
    const unsigned short* __restrict__ A, const unsigned short* __restrict__ Bt,
    unsigned short* __restrict__ Ck, unsigned short* __restrict__ vt, int K) {
  __shared__ unsigned short As[1024 * 8];
  __shared__ unsigned short Bs[1024 * 8];
  const int tid = threadIdx.x;
  const int m0 = blockIdx.y * 128, n0 = blockIdx.x * 128;
  const int wave = tid >> 6, lane = tid & 63;
  const int wm = (wave >> 1) * 64, wn = (wave & 1) * 64;
  const int l16 = lane & 15, quad = lane >> 4;

  f32x4 acc[4][4];
#pragma unroll
  for (int i = 0; i < 4; ++i)
#pragma unroll
    for (int j = 0; j < 4; ++j)
#pragma unroll
      for (int r = 0; r < 4; ++r) acc[i][j][r] = 0.f;

  for (int k0 = 0; k0 < K; k0 += 64) {
    __syncthreads();
#pragma unroll
    for (int it = 0; it < 4; ++it) {
      int c = it * 256 + tid;
      int m = c >> 3, kc = (c & 7) ^ (m & 7);
      g2lds16(&A[(size_t)(m0 + m) * K + k0 + kc * 8], &As[c * 8]);
    }
#pragma unroll
    for (int it = 0; it < 4; ++it) {
      int c = it * 256 + tid;
      int n = c >> 3, kc = (c & 7) ^ (n & 7);
      g2lds16(&Bt[(size_t)(n0 + n) * K + k0 + kc * 8], &Bs[c * 8]);
    }
    __syncthreads();

#pragma unroll
    for (int ks = 0; ks < 2; ++ks) {
      bf16x8 af[4], bfr[4];
#pragma unroll
      for (int mi = 0; mi < 4; ++mi) {
        int m = wm + mi * 16 + l16;
        af[mi] = *reinterpret_cast<const bf16x8*>(
            &As[(m * 8 + ((ks * 4 + quad) ^ (m & 7))) * 8]);
      }
#pragma unroll
      for (int ni = 0; ni < 4; ++ni) {
        int n = wn + ni * 16 + l16;
        bfr[ni] = *reinterpret_cast<const bf16x8*>(
            &Bs[(n * 8 + ((ks * 4 + quad) ^ (n & 7))) * 8]);
      }
#pragma unroll
      for (int mi = 0; mi < 4; ++mi)
#pragma unroll
        for (int ni = 0; ni < 4; ++ni)
          acc[mi][ni] = __builtin_amdgcn_mfma_f32_16x16x32_bf16(
              af[mi], bfr[ni], acc[mi][ni], 0, 0, 0);
    }
  }

  if (n0 < 1024) {
    // k_c: accumulate onto rope'd k_r
#pragma unroll
    for (int mi = 0; mi < 4; ++mi)
#pragma unroll
      for (int ni = 0; ni < 4; ++ni) {
        int row = m0 + wm + mi * 16 + quad * 4;
        int col = n0 + wn + ni * 16 + l16;
#pragma unroll
        for (int r = 0; r < 4; ++r) {
          size_t idx = (size_t)(row + r) * 1024 + col;
          Ck[idx] = f2b(acc[mi][ni][r] + b2f(Ck[idx]));
        }
      }
  } else {
    // v_c -> Vt[b,h,d,sigma^-1(l)] direct, 8B stores
    const int L = 2048;
#pragma unroll
    for (int mi = 0; mi < 4; ++mi)
#pragma unroll
      for (int ni = 0; ni < 4; ++ni) {
        int row = m0 + wm + mi * 16 + quad * 4;       // row % 4 == 0
        int col = n0 - 1024 + wn + ni * 16 + l16;     // h*64 + d
        int l = row & (L - 1);
        int bh = ((row >> 11) << 4) | (col >> 6);
        int d = col & 63;
        int s = (l & ~63) | (((l >> 5) & 1) << 5) | (((l >> 3) & 1) << 4) |
                (((l >> 2) & 1) << 3) | (((l >> 4) & 1) << 2);
        ushort4v w;
#pragma unroll
        for (int r = 0; r < 4; ++r) w[r] = f2b(acc[mi][ni][r]);
        *reinterpret_cast<ushort4v*>(
            &vt[(size_t)bh * 64 * L + (size_t)d * L + s]) = w;
      }
  }
}

// ---------- flash v15: 8 waves, 512 thr, in-block KV-split ----------
// waves 0-3 process KV [0,L/2), waves 4-7 KV [L/2,L), same 128 q rows.
// No max-subtraction -> O and l additive over key ranges: half-1 waves
// write (oacc,lacc) to LDS once at the end; half-0 adds, normalizes, stores.
__global__ __launch_bounds__(512) void flash15_kernel(
    const unsigned short* __restrict__ qs, const unsigned short* __restrict__ ks,
    const unsigned short* __restrict__ vt, unsigned short* __restrict__ o,
    int L) {
  // [kv={K,V}][half][dbuf][64x64 swizzled]  = 64KB total
  __shared__ unsigned short KV[2][2][2][512 * 8];
  const int tid = threadIdx.x;
  const int wave = tid >> 6, lane = tid & 63;
  const int half = wave >> 2;                  // KV half this wave works on
  const int l16 = lane & 15, quad = lane >> 4;
  const int bh = blockIdx.y;                   // b*16 + h
  const int qb = blockIdx.x * 128 + (wave & 3) * 32;  // this wave's 32 q rows
  const size_t base = ((size_t)(bh >> 4) * L) * 1024 + (bh & 15) * 64;
  const size_t vtbase = (size_t)bh * 64 * L;
  const int kvoff = half * (L >> 1);           // key offset of this half
  const int sid = tid & 255;                   // staging lane within half

  bf16x8 aq[2][2];
#pragma unroll
  for (int mt = 0; mt < 2; ++mt) {
    size_t qrow = base + (size_t)(qb + mt * 16 + l16) * 1024;
    aq[mt][0] = *reinterpret_cast<const bf16x8*>(&qs[qrow + quad * 8]);
    aq[mt][1] = *reinterpret_cast<const bf16x8*>(&qs[qrow + 32 + quad * 8]);
  }

  ushort8v onesu;
#pragma unroll
  for (int j = 0; j < 8; ++j) onesu[j] = 0x3F80;  // bf16 1.0
  bf16x8 ones = *reinterpret_cast<bf16x8*>(&onesu);

  f32x4 oacc[2][4];
  f32x4 lacc[2];
#pragma unroll
  for (int mt = 0; mt < 2; ++mt) {
#pragma unroll
    for (int r = 0; r < 4; ++r) lacc[mt][r] = 0.f;
#pragma unroll
    for (int nt = 0; nt < 4; ++nt)
#pragma unroll
      for (int r = 0; r < 4; ++r) oacc[mt][nt][r] = 0.f;
  }

  const int T = L / 128;   // 16 tiles per half
  // prologue: each half's 256 threads stage that half's tile 0
#pragma unroll
  for (int it = 0; it < 2; ++it) {
    int c = it * 256 + sid;                    // [0,512)
    int key = c >> 3, dc = (c & 7) ^ (key & 7);
    g2lds16(&ks[base + (size_t)(kvoff + key) * 1024 + dc * 8],
            &KV[0][half][0][c * 8]);
  }
#pragma unroll
  for (int it = 0; it < 2; ++it) {
    int c = it * 256 + sid;
    int d = c >> 3, kc = (c & 7) ^ (d & 7);
    g2lds16(&vt[vtbase + (size_t)d * L + kvoff + kc * 8],
            &KV[1][half][0][c * 8]);
  }

  for (int t = 0; t < T; ++t) {
    __syncthreads();   // drains stage(t); prior-buf readers done
    if (t + 1 < T) {
      int k0 = kvoff + (t + 1) * 64, nb = (t + 1) & 1;
#pragma unroll
      for (int it = 0; it < 2; ++it) {
        int c = it * 256 + sid;
        int key = c >> 3, dc = (c & 7) ^ (key & 7);
        g2lds16(&ks[base + (size_t)(k0 + key) * 1024 + dc * 8],
                &KV[0][half][nb][c * 8]);
      }
#pragma unroll
      for (int it = 0; it < 2; ++it) {
        int c = it * 256 + sid;
        int d = c >> 3, kc = (c & 7) ^ (d & 7);
        g2lds16(&vt[vtbase + (size_t)d * L + k0 + kc * 8],
                &KV[1][half][nb][c * 8]);
      }
    }
    const int cb = t & 1;
    const unsigned short* Ks = &KV[0][half][cb][0];
    const unsigned short* Vs = &KV[1][half][cb][0];

    // S^T = K Q^T for BOTH m-tiles; K fragments read once.
    f32x4 st[2][4];
#pragma unroll
    for (int nt = 0; nt < 4; ++nt) {
      int key = nt * 16 + l16;
      int dc0 = quad ^ (key & 7);
      int dc1 = (4 + quad) ^ (key & 7);
      bf16x8 bk0 = *reinterpret_cast<const bf16x8*>(&Ks[(key * 8 + dc0) * 8]);
      bf16x8 bk1 = *reinterpret_cast<const bf16x8*>(&Ks[(key * 8 + dc1) * 8]);
#pragma unroll
      for (int mt = 0; mt < 2; ++mt) {
        f32x4 z; z[0] = z[1] = z[2] = z[3] = 0.f;
        z = __builtin_amdgcn_mfma_f32_16x16x32_bf16(bk0, aq[mt][0], z, 0, 0, 0);
        z = __builtin_amdgcn_mfma_f32_16x16x32_bf16(bk1, aq[mt][1], z, 0, 0, 0);
        st[mt][nt] = z;
      }
    }

    // exp2 -> ap frags by pure register renaming (key-permutation sigma)
    bf16x8 ap[2][2];
#pragma unroll
    for (int mt = 0; mt < 2; ++mt) {
#pragma unroll
      for (int hf = 0; hf < 2; ++hf)
#pragma unroll
        for (int w = 0; w < 4; ++w) {
          int nt = 2 * hf + (w >> 1), p = w & 1;
          ap[mt][hf][2 * w] =
              (__bf16)__builtin_amdgcn_exp2f(st[mt][nt][2 * p]);
          ap[mt][hf][2 * w + 1] =
              (__bf16)__builtin_amdgcn_exp2f(st[mt][nt][2 * p + 1]);
        }
      lacc[mt] = __builtin_amdgcn_mfma_f32_16x16x32_bf16(ap[mt][0], ones,
                                                         lacc[mt], 0, 0, 0);
      lacc[mt] = __builtin_amdgcn_mfma_f32_16x16x32_bf16(ap[mt][1], ones,
                                                         lacc[mt], 0, 0, 0);
    }

    // O += P V (V fragments read once, reused by both m-tiles)
#pragma unroll
    for (int nt = 0; nt < 4; ++nt) {
      int d = nt * 16 + l16;
#pragma unroll
      for (int hf = 0; hf < 2; ++hf) {
        int kc = (hf * 4 + quad) ^ (d & 7);
        bf16x8 bv = *reinterpret_cast<const bf16x8*>(&Vs[(d * 8 + kc) * 8]);
#pragma unroll
        for (int mt = 0; mt < 2; ++mt)
          oacc[mt][nt] = __builtin_amdgcn_mfma_f32_16x16x32_bf16(
              ap[mt][hf], bv, oacc[mt][nt], 0, 0, 0);
      }
    }
  }

  // ---- combine halves in LDS (O and l are additive; no max used) ----
  __syncthreads();                 // all K/V reads done; LDS reusable
  float* cbuf = (float*)&KV[0][0][0][0];   // 45056B needed <= 64KB
  if (half == 1) {
    int slot = ((wave - 4) * 64 + lane) * 44;   // stride 44 f32 (16B-aligned)
#pragma unroll
    for (int mt = 0; mt < 2; ++mt) {
#pragma unroll
      for (int nt = 0; nt < 4; ++nt)
        *reinterpret_cast<f32x4*>(&cbuf[slot + (mt * 4 + nt) * 4]) =
            oacc[mt][nt];
      *reinterpret_cast<f32x4*>(&cbuf[slot + 32 + mt * 4]) = lacc[mt];
    }
  }
  __syncthreads();
  if (half == 0) {
    int slot = (wave * 64 + lane) * 44;
#pragma unroll
    for (int mt = 0; mt < 2; ++mt) {
#pragma unroll
      for (int nt = 0; nt < 4; ++nt) {
        f32x4 ov = *reinterpret_cast<const f32x4*>(
            &cbuf[slot + (mt * 4 + nt) * 4]);
#pragma unroll
        for (int r = 0; r < 4; ++r) oacc[mt][nt][r] += ov[r];
      }
      f32x4 lv = *reinterpret_cast<const f32x4*>(&cbuf[slot + 32 + mt * 4]);
#pragma unroll
      for (int r = 0; r < 4; ++r) lacc[mt][r] += lv[r];
    }
#pragma unroll
    for (int mt = 0; mt < 2; ++mt)
#pragma unroll
      for (int r = 0; r < 4; ++r) {
        float inv = __builtin_amdgcn_rcpf(lacc[mt][r]);
        int q = qb + mt * 16 + quad * 4 + r;
#pragma unroll
        for (int nt = 0; nt < 4; ++nt)
          o[base + (size_t)q * 1024 + nt * 16 + l16] =
              f2b(oacc[mt][nt][r] * inv);
      }
  }
}

// ---------------- driver ----------------
extern "C" void kernel_launch(void* const* d_in, const int* in_sizes, int n_in,
                              void* d_out, int out_size, void* d_ws, size_t ws_size,
                              hipStream_t stream) {
  const float* X    = (const float*)d_in[0];
  const float* tq   = (const float*)d_in[1];
  const float* tk   = (const float*)d_in[2];
  const float* wkvc = (const float*)d_in[3];
  const float* wkc  = (const float*)d_in[4];
  const float* wvc  = (const float*)d_in[5];
  const float* wqr  = (const float*)d_in[6];
  const float* wkr  = (const float*)d_in[7];
  const float* wo   = (const float*)d_in[8];

  const int D = 1024, DC = 128, L = 2048;
  const int M = in_sizes[0] / D;       // B*L
  const int B = M / L;
  const int NBH = B * 16;
  (void)n_in; (void)out_size; (void)ws_size;

  unsigned short* p = (unsigned short*)d_ws;
  auto take = [&](size_t n) { unsigned short* r = p; p += n; return r; };
  unsigned short* Xb    = take((size_t)M * D);
  unsigned short* qsb   = take((size_t)M * D);
  unsigned short* ksb   = take((size_t)M * D);
  unsigned short* vcb   = take((size_t)M * D);
  unsigned short* ckv   = take((size_t)M * DC);
  unsigned short* Wbig  = take((size_t)(2 * D + DC) * D);   // [wqr|wkr|wkvc]^T
  unsigned short* Wkcvc = take((size_t)(2 * D) * DC);       // [wkc|wvc]^T
  unsigned short* WoT   = take((size_t)D * D);
  f32x2* ctab = (f32x2*)take((size_t)M * 32 * 4);           // M*32 float2
  unsigned short* vtb   = Xb;   // Xb dead after fused3 gemm; fused2 writes Vt here
  unsigned short* obuf  = vcb;  // vcb unused otherwise; flash O lands here

  // prep: cvt + all 6 weight transposes + rope cos table in ONE launch
  const int n8 = M * D / 8;
  const int cvtb = (n8 + 255) / 256;
  const int ropeb = M / 8;             // M*32 threads / 256
  prep_kernel<<<cvtb + 864 + ropeb, 256, 0, stream>>>(
      X, Xb, cvtb, n8,
      wqr,  Wbig,
      wkr,  Wbig + (size_t)D * D,
      wkvc, Wbig + (size_t)2 * D * D,
      wkc,  Wkcvc,
      wvc,  Wkcvc + (size_t)D * DC,
      wo,   WoT,
      tq, tk, ctab);

  {
    // 1D grid 17*32 = 544 = 8*68, XCD-chunk-swizzled in-kernel
    gemm_fused3<<<(2 * D + DC) / 128 * (M / 128), 256, 0, stream>>>(
        Xb, Wbig, qsb, ksb, ckv, ctab, D);
  }
  {
    dim3 g(2 * D / 128, M / 128);                          // (16, 32)
    gemm_fused2<<<g, 256, 0, stream>>>(ckv, Wkcvc, ksb, vtb, DC);
  }

  dim3 fg(L / 128, NBH);                                   // (16, 32)
  flash15_kernel<<<fg, 512, 0, stream>>>(qsb, ksb, vtb, obuf, L);

  {
    // 1D grid (D/128)*(M/64) = 8*64 = 512, XCD-chunk-swizzled in-kernel
    gemm_bt<64, float, false><<<(D / 128) * (M / 64), 256, 0, stream>>>(
        obuf, WoT, (float*)d_out, M, D, D);
  }
}